// Round 8
// baseline (283.279 us; speedup 1.0000x reference)
//
#include <hip/hip_runtime.h>

typedef _Float16 f16;
typedef _Float16 f16x8 __attribute__((ext_vector_type(8)));
typedef __fp16   fp16x2 __attribute__((ext_vector_type(2)));
typedef float    f32x16 __attribute__((ext_vector_type(16)));
typedef float    f32x4  __attribute__((ext_vector_type(4)));
typedef unsigned int u32;
typedef unsigned int u32x4 __attribute__((ext_vector_type(4)));

#define NPTS 262144

// ---- packed layout in d_ws (per net, net stride NET_F16 f16) ----
// Weight image = 70 contiguous 8KB chunks (512 x u32x4):
//   net0: L0 (1) | L1 (16) | L2 (16) | L3 (2) = 35 chunks; net1 same.
// Chunk contents: frag[mt][lane][8 f16] (L3: frag[kt][lane][8]).
// A-frag (mfma_f32_32x32x16_f16): A[m][k], m = 32*mt + (lane&31);
//   k(L0) = 8*hi + j canonical (zero-padded); k(L1/L2/L3) PERMUTED:
//   kphys(kt,hi,j) = 32*(kt>>1) + 16*(kt&1) + (j&3) + 8*(j>>2) + 4*hi
//   == C/D layout of previous layer's tile -> zero-shuffle epilogue.
// f32 biases at byte BIAS_BYTE, 800 floats/net, packed in C/D order.
#define NET_F16   143360
#define L1_OFF    4096
#define L2_OFF    69632
#define L3_OFF    135168
#define BIAS_BYTE 573440
#define NCHUNK    70

static __device__ __forceinline__ u32 pkrtz(float a, float b) {
    fp16x2 h = __builtin_amdgcn_cvt_pkrtz(a, b);
    return __builtin_bit_cast(u32, h);
}
static __device__ __forceinline__ u32 relu_pk(float a, float b) {
    return pkrtz(fmaxf(a, 0.0f), fmaxf(b, 0.0f));
}

// ---------------- weight/bias packing kernel (unchanged, proven) ----------------
__global__ void prep_kernel(
    const float* __restrict__ dW0, const float* __restrict__ db0,
    const float* __restrict__ dW1, const float* __restrict__ db1,
    const float* __restrict__ dW2, const float* __restrict__ db2,
    const float* __restrict__ dW3, const float* __restrict__ db3,
    const float* __restrict__ sW0, const float* __restrict__ sb0,
    const float* __restrict__ sW1, const float* __restrict__ sb1,
    const float* __restrict__ sW2, const float* __restrict__ sb2,
    const float* __restrict__ sW3, const float* __restrict__ sb3,
    f16* __restrict__ wpk, float* __restrict__ bpk)
{
    const int ROWS = 17920;
    int t = blockIdx.x * 256 + threadIdx.x;
    if (t < 2 * ROWS) {
        int net = (t >= ROWS) ? 1 : 0;
        int r = t - net * ROWS;
        const float* W0 = net ? sW0 : dW0;
        const float* W1 = net ? sW1 : dW1;
        const float* W2 = net ? sW2 : dW2;
        const float* W3 = net ? sW3 : dW3;
        int K0 = net ? 8 : 3;
        f16* o = wpk + net * NET_F16;
        if (r < 512) {                                   // L0: canonical slots
            int lane = r & 63;
            int m  = 32 * (r >> 6) + (lane & 31);
            int kb = 8 * (lane >> 5);
            f16* q = o + r * 8;
            #pragma unroll
            for (int j = 0; j < 8; ++j) {
                int k = kb + j;
                q[j] = (f16)((k < K0) ? W0[k * 256 + m] : 0.0f);
            }
        } else if (r < 512 + 8192) {                     // L1: permuted k
            int rr = r - 512;
            int lane = rr & 63;
            int hh = lane >> 5;
            int m  = 32 * ((rr >> 6) & 7) + (lane & 31);
            int kt = rr >> 9;
            f16* q = o + L1_OFF + rr * 8;
            #pragma unroll
            for (int j = 0; j < 8; ++j) {
                int kp = 32 * (kt >> 1) + 16 * (kt & 1) + (j & 3) + 8 * (j >> 2) + 4 * hh;
                q[j] = (f16)W1[kp * 256 + m];
            }
        } else if (r < 512 + 16384) {                    // L2: permuted k
            int rr = r - (512 + 8192);
            int lane = rr & 63;
            int hh = lane >> 5;
            int m  = 32 * ((rr >> 6) & 7) + (lane & 31);
            int kt = rr >> 9;
            f16* q = o + L2_OFF + rr * 8;
            #pragma unroll
            for (int j = 0; j < 8; ++j) {
                int kp = 32 * (kt >> 1) + 16 * (kt & 1) + (j & 3) + 8 * (j >> 2) + 4 * hh;
                q[j] = (f16)W2[kp * 256 + m];
            }
        } else {                                         // L3: permuted k
            int rr = r - (512 + 16384);
            int lane = rr & 63;
            int hh = lane >> 5;
            int m  = lane & 31;
            int kt = rr >> 6;
            f16* q = o + L3_OFF + rr * 8;
            #pragma unroll
            for (int j = 0; j < 8; ++j) {
                int kp = 32 * (kt >> 1) + 16 * (kt & 1) + (j & 3) + 8 * (j >> 2) + 4 * hh;
                q[j] = (f16)((m < 3) ? W3[kp * 3 + m] : 0.0f);
            }
        }
    } else if (t < 2 * ROWS + 1600) {                    // biases (C/D order)
        int tb = t - 2 * ROWS;
        int net = (tb >= 800) ? 1 : 0;
        int i = tb - net * 800;
        float val;
        if (i < 768) {
            int layer = i >> 8;
            const float* bl = net ? (layer == 0 ? sb0 : layer == 1 ? sb1 : sb2)
                                  : (layer == 0 ? db0 : layer == 1 ? db1 : db2);
            int q  = i & 255;
            int rg = q & 15, h = (q >> 4) & 1;
            int m  = 32 * (q >> 5) + (rg & 3) + 8 * (rg >> 2) + 4 * h;
            val = bl[m];
        } else {
            int q  = i - 768;
            int rg = q & 15, h = q >> 4;
            int m  = (rg & 3) + 8 * (rg >> 2) + 4 * h;
            const float* b3 = net ? sb3 : db3;
            val = (m < 3) ? b3[m] : 0.0f;
        }
        bpk[net * 800 + i] = val;
    }
}

// One pipeline step: barrier (compiler-inserted full drain => chunk c landed
// in buf[c&1] from ALL waves; all reads of chunk c-1 completed), then issue
// chunk c+1 into the buffer that held c-1 (safe WAR), then compute chunk c.
// Wave wv stages 2KB: rows wv*128..wv*128+127 (two lane-linear 16B DMAs).
#define STEP_SYNC_PREFETCH() do {                                               \
    __syncthreads();                                                            \
    int cn_ = c + 1;                                                            \
    if (cn_ < NCHUNK) {                                                         \
        const u32x4* gsrc_ = ws + cn_ * 512 + wv * 128 + lane;                  \
        u32x4* ldst_ = &ring[cn_ & 1][wv * 128];                                \
        __builtin_amdgcn_global_load_lds(                                       \
            (const __attribute__((address_space(1))) void*)gsrc_,               \
            (__attribute__((address_space(3))) void*)ldst_, 16, 0, 0);          \
        __builtin_amdgcn_global_load_lds(                                       \
            (const __attribute__((address_space(1))) void*)(gsrc_ + 64),        \
            (__attribute__((address_space(3))) void*)(ldst_ + 64), 16, 0, 0);   \
    }                                                                           \
} while (0)

// bias-init one acc tile from LDS bias block (C/D order)
#define BINIT(dst, boff) do {                                                   \
    const f32x4* b4_ = (const f32x4*)(biasl + (boff) + hi * 16);                \
    const f32x4 v0_ = b4_[0], v1_ = b4_[1], v2_ = b4_[2], v3_ = b4_[3];         \
    _Pragma("unroll")                                                           \
    for (int j = 0; j < 4; ++j) {                                               \
        (dst)[j] = v0_[j]; (dst)[4 + j] = v1_[j];                               \
        (dst)[8 + j] = v2_[j]; (dst)[12 + j] = v3_[j];                          \
    }                                                                           \
} while (0)

// Zero-shuffle epilogue: C/D regs -> ReLU -> f16 -> next-layer B-frags in place.
#define EPI() do {                                                              \
    _Pragma("unroll")                                                           \
    for (int mt = 0; mt < 8; ++mt) {                                            \
        _Pragma("unroll")                                                       \
        for (int q = 0; q < 2; ++q) {                                           \
            u32x4 w;                                                            \
            w[0] = relu_pk(acc[mt][8*q+0], acc[mt][8*q+1]);                     \
            w[1] = relu_pk(acc[mt][8*q+2], acc[mt][8*q+3]);                     \
            w[2] = relu_pk(acc[mt][8*q+4], acc[mt][8*q+5]);                     \
            w[3] = relu_pk(acc[mt][8*q+6], acc[mt][8*q+7]);                     \
            xf[2*mt+q] = w;                                                     \
        }                                                                       \
    }                                                                           \
} while (0)

// ---------------- fused dual-MLP kernel ----------------
// 256 thr = 4 waves/block, 32 points/wave, 128 points/block, grid 2048.
// Shared double-buffered chunk pipeline over the 70-chunk weight stream;
// plain __syncthreads() (full drain) -- no inline-asm sync.
__launch_bounds__(256, 2)
__global__ void mlp_kernel(const float* __restrict__ gn, const float* __restrict__ gv,
                           const float* __restrict__ gro, const float* __restrict__ gr0,
                           const f16* __restrict__ wpk, const float* __restrict__ bpk,
                           float* __restrict__ out)
{
    __shared__ u32x4 ring[2][512];                 // 16KB double buffer
    __shared__ __align__(16) float biasl[1600];    // 6.4KB biases

    const int tid  = threadIdx.x;
    const int wv   = tid >> 6;
    const int lane = tid & 63;
    const int l32  = lane & 31;
    const int hi   = lane >> 5;
    const int p    = blockIdx.x * 128 + wv * 32 + l32;
    const u32x4* ws = (const u32x4*)wpk;           // 70-chunk contiguous stream

    // ---- biases -> LDS ----
    biasl[tid]        = bpk[tid];
    biasl[tid + 256]  = bpk[tid + 256];
    biasl[tid + 512]  = bpk[tid + 512];
    biasl[tid + 768]  = bpk[tid + 768];
    biasl[tid + 1024] = bpk[tid + 1024];
    biasl[tid + 1280] = bpk[tid + 1280];
    if (tid < 64) biasl[tid + 1536] = bpk[tid + 1536];

    // ---- prologue: stage chunk 0 ----
    {
        const u32x4* gsrc_ = ws + wv * 128 + lane;
        u32x4* ldst_ = &ring[0][wv * 128];
        __builtin_amdgcn_global_load_lds(
            (const __attribute__((address_space(1))) void*)gsrc_,
            (__attribute__((address_space(3))) void*)ldst_, 16, 0, 0);
        __builtin_amdgcn_global_load_lds(
            (const __attribute__((address_space(1))) void*)(gsrc_ + 64),
            (__attribute__((address_space(3))) void*)(ldst_ + 64), 16, 0, 0);
    }

    // ---- inputs ----
    u32x4 xd = {0,0,0,0}, xs = {0,0,0,0};
    bool vis = false;
    if (hi == 0) {               // hi lanes hold k=8..15 (zero-padded)
        float nx = gn[3*p], ny = gn[3*p+1], nz = gn[3*p+2];
        float vx = gv[3*p], vy = gv[3*p+1], vz = gv[3*p+2];
        float ro = gro[p], rr = gr0[p];
        float ni = 1.0f / fmaxf(sqrtf(nx*nx + ny*ny + nz*nz), 1e-12f);
        float vi = 1.0f / fmaxf(sqrtf(vx*vx + vy*vy + vz*vz), 1e-12f);
        nx *= ni; ny *= ni; nz *= ni; vx *= vi; vy *= vi; vz *= vi;
        vis = (nx*vx + ny*vy + nz*vz) > 0.0f;
        xd[0] = pkrtz(nx, ny); xd[1] = pkrtz(nz, 0.0f);
        xs[0] = xd[0];         xs[1] = pkrtz(nz, vx);
        xs[2] = pkrtz(vy, vz); xs[3] = pkrtz(ro, rr);
    }

    f32x16 acc[8];    // 128 regs (AGPR-eligible)
    u32x4  xf[16];    // 64 VGPRs
    int c = 0;        // global chunk index (0..69)

    #pragma unroll 1
    for (int net = 0; net < 2; ++net) {
        const int bb = net * 800;
        const f16x8 xh0 = __builtin_bit_cast(f16x8, net ? xs : xd);

        // ---------- L0 (1 chunk) ----------
        STEP_SYNC_PREFETCH();
        {
            const u32x4* bufq = &ring[c & 1][0];
            #pragma unroll
            for (int mt = 0; mt < 8; ++mt) {
                f32x16 ci;
                BINIT(ci, bb + mt * 32);
                const f16x8 a = __builtin_bit_cast(f16x8, bufq[mt * 64 + lane]);
                acc[mt] = __builtin_amdgcn_mfma_f32_32x32x16_f16(a, xh0, ci, 0, 0, 0);
            }
        }
        ++c;
        EPI();

        // ---------- L1, L2 (16 chunks each) ----------
        #pragma unroll 1
        for (int layer = 0; layer < 2; ++layer) {
            #pragma unroll
            for (int mt = 0; mt < 8; ++mt) BINIT(acc[mt], bb + 256 + layer * 256 + mt * 32);
            #pragma unroll
            for (int kt = 0; kt < 16; ++kt) {
                STEP_SYNC_PREFETCH();
                const u32x4* bufq = &ring[c & 1][0];
                const f16x8 xh = __builtin_bit_cast(f16x8, xf[kt]);
                #pragma unroll
                for (int mt = 0; mt < 8; ++mt) {
                    const f16x8 a = __builtin_bit_cast(f16x8, bufq[mt * 64 + lane]);
                    acc[mt] = __builtin_amdgcn_mfma_f32_32x32x16_f16(a, xh, acc[mt], 0, 0, 0);
                }
                ++c;
            }
            EPI();
        }

        // ---------- L3: 256 -> 3 (2 chunks) ----------
        {
            f32x16 c3;
            BINIT(c3, bb + 768);
            #pragma unroll 1
            for (int half = 0; half < 2; ++half) {
                STEP_SYNC_PREFETCH();
                const u32x4* bufq = &ring[c & 1][0];
                #pragma unroll
                for (int i = 0; i < 8; ++i) {
                    const f16x8 a = __builtin_bit_cast(f16x8, bufq[i * 64 + lane]);
                    c3 = __builtin_amdgcn_mfma_f32_32x32x16_f16(
                            a, __builtin_bit_cast(f16x8, xf[half * 8 + i]), c3, 0, 0, 0);
                }
                ++c;
            }
            if (hi == 0) {
                float* op = out + net * (NPTS * 3) + p * 3;
                op[0] = vis ? c3[0] : 0.0f;
                op[1] = vis ? c3[1] : 0.0f;
                op[2] = vis ? c3[2] : 0.0f;
            }
        }
    }
}

extern "C" void kernel_launch(void* const* d_in, const int* in_sizes, int n_in,
                              void* d_out, int out_size, void* d_ws, size_t ws_size,
                              hipStream_t stream)
{
    f16*   wpk = (f16*)d_ws;
    float* bpk = (float*)((char*)d_ws + BIAS_BYTE);

    prep_kernel<<<147, 256, 0, stream>>>(
        (const float*)d_in[4],  (const float*)d_in[5],
        (const float*)d_in[6],  (const float*)d_in[7],
        (const float*)d_in[8],  (const float*)d_in[9],
        (const float*)d_in[10], (const float*)d_in[11],
        (const float*)d_in[12], (const float*)d_in[13],
        (const float*)d_in[14], (const float*)d_in[15],
        (const float*)d_in[16], (const float*)d_in[17],
        (const float*)d_in[18], (const float*)d_in[19],
        wpk, bpk);

    mlp_kernel<<<2048, 256, 0, stream>>>(
        (const float*)d_in[0], (const float*)d_in[1],
        (const float*)d_in[2], (const float*)d_in[3],
        wpk, bpk, (float*)d_out);
}

// Round 9
// 161.687 us; speedup vs baseline: 1.7520x; 1.7520x over previous
//
#include <hip/hip_runtime.h>

typedef _Float16 f16;
typedef _Float16 f16x8 __attribute__((ext_vector_type(8)));
typedef __fp16   fp16x2 __attribute__((ext_vector_type(2)));
typedef float    f32x16 __attribute__((ext_vector_type(16)));
typedef float    f32x4  __attribute__((ext_vector_type(4)));
typedef unsigned int u32;
typedef unsigned int u32x4 __attribute__((ext_vector_type(4)));

#define NPTS 262144

// ---- packed layout in d_ws (per net, net stride NET_F16 f16) ----
// Weight image = 70 contiguous 8KB chunks (512 x u32x4):
//   net0: L0 (1) | L1 (16) | L2 (16) | L3 (2) = 35 chunks; net1 same.
// Chunk contents: frag[mt][lane][8 f16] (L3: frag[kt][lane][8]).
// A-frag (mfma_f32_32x32x16_f16): A[m][k], m = 32*mt + (lane&31);
//   k(L0) = 8*hi + j canonical (zero-padded); k(L1/L2/L3) PERMUTED:
//   kphys(kt,hi,j) = 32*(kt>>1) + 16*(kt&1) + (j&3) + 8*(j>>2) + 4*hi
//   == C/D layout of previous layer's tile -> zero-shuffle epilogue.
// f32 biases at byte BIAS_BYTE, 800 floats/net, packed in C/D order.
#define NET_F16   143360
#define L1_OFF    4096
#define L2_OFF    69632
#define L3_OFF    135168
#define BIAS_BYTE 573440
#define NCHUNK    70

static __device__ __forceinline__ u32 pkrtz(float a, float b) {
    fp16x2 h = __builtin_amdgcn_cvt_pkrtz(a, b);
    return __builtin_bit_cast(u32, h);
}
static __device__ __forceinline__ u32 relu_pk(float a, float b) {
    return pkrtz(fmaxf(a, 0.0f), fmaxf(b, 0.0f));
}

// ---------------- weight/bias packing kernel (unchanged, proven) ----------------
__global__ void prep_kernel(
    const float* __restrict__ dW0, const float* __restrict__ db0,
    const float* __restrict__ dW1, const float* __restrict__ db1,
    const float* __restrict__ dW2, const float* __restrict__ db2,
    const float* __restrict__ dW3, const float* __restrict__ db3,
    const float* __restrict__ sW0, const float* __restrict__ sb0,
    const float* __restrict__ sW1, const float* __restrict__ sb1,
    const float* __restrict__ sW2, const float* __restrict__ sb2,
    const float* __restrict__ sW3, const float* __restrict__ sb3,
    f16* __restrict__ wpk, float* __restrict__ bpk)
{
    const int ROWS = 17920;
    int t = blockIdx.x * 256 + threadIdx.x;
    if (t < 2 * ROWS) {
        int net = (t >= ROWS) ? 1 : 0;
        int r = t - net * ROWS;
        const float* W0 = net ? sW0 : dW0;
        const float* W1 = net ? sW1 : dW1;
        const float* W2 = net ? sW2 : dW2;
        const float* W3 = net ? sW3 : dW3;
        int K0 = net ? 8 : 3;
        f16* o = wpk + net * NET_F16;
        if (r < 512) {                                   // L0: canonical slots
            int lane = r & 63;
            int m  = 32 * (r >> 6) + (lane & 31);
            int kb = 8 * (lane >> 5);
            f16* q = o + r * 8;
            #pragma unroll
            for (int j = 0; j < 8; ++j) {
                int k = kb + j;
                q[j] = (f16)((k < K0) ? W0[k * 256 + m] : 0.0f);
            }
        } else if (r < 512 + 8192) {                     // L1: permuted k
            int rr = r - 512;
            int lane = rr & 63;
            int hh = lane >> 5;
            int m  = 32 * ((rr >> 6) & 7) + (lane & 31);
            int kt = rr >> 9;
            f16* q = o + L1_OFF + rr * 8;
            #pragma unroll
            for (int j = 0; j < 8; ++j) {
                int kp = 32 * (kt >> 1) + 16 * (kt & 1) + (j & 3) + 8 * (j >> 2) + 4 * hh;
                q[j] = (f16)W1[kp * 256 + m];
            }
        } else if (r < 512 + 16384) {                    // L2: permuted k
            int rr = r - (512 + 8192);
            int lane = rr & 63;
            int hh = lane >> 5;
            int m  = 32 * ((rr >> 6) & 7) + (lane & 31);
            int kt = rr >> 9;
            f16* q = o + L2_OFF + rr * 8;
            #pragma unroll
            for (int j = 0; j < 8; ++j) {
                int kp = 32 * (kt >> 1) + 16 * (kt & 1) + (j & 3) + 8 * (j >> 2) + 4 * hh;
                q[j] = (f16)W2[kp * 256 + m];
            }
        } else {                                         // L3: permuted k
            int rr = r - (512 + 16384);
            int lane = rr & 63;
            int hh = lane >> 5;
            int m  = lane & 31;
            int kt = rr >> 6;
            f16* q = o + L3_OFF + rr * 8;
            #pragma unroll
            for (int j = 0; j < 8; ++j) {
                int kp = 32 * (kt >> 1) + 16 * (kt & 1) + (j & 3) + 8 * (j >> 2) + 4 * hh;
                q[j] = (f16)((m < 3) ? W3[kp * 3 + m] : 0.0f);
            }
        }
    } else if (t < 2 * ROWS + 1600) {                    // biases (C/D order)
        int tb = t - 2 * ROWS;
        int net = (tb >= 800) ? 1 : 0;
        int i = tb - net * 800;
        float val;
        if (i < 768) {
            int layer = i >> 8;
            const float* bl = net ? (layer == 0 ? sb0 : layer == 1 ? sb1 : sb2)
                                  : (layer == 0 ? db0 : layer == 1 ? db1 : db2);
            int q  = i & 255;
            int rg = q & 15, h = (q >> 4) & 1;
            int m  = 32 * (q >> 5) + (rg & 3) + 8 * (rg >> 2) + 4 * h;
            val = bl[m];
        } else {
            int q  = i - 768;
            int rg = q & 15, h = q >> 4;
            int m  = (rg & 3) + 8 * (rg >> 2) + 4 * h;
            const float* b3 = net ? sb3 : db3;
            val = (m < 3) ? b3[m] : 0.0f;
        }
        bpk[net * 800 + i] = val;
    }
}

// One pipeline step: barrier (compiler-inserted full drain => chunk c landed
// in buf[c&1] from ALL waves; all reads of chunk c-1 completed), then issue
// chunk c+1 into the buffer that held c-1 (safe WAR), then compute chunk c.
// Wave wv stages 2KB: rows wv*128..wv*128+127 (two lane-linear 16B DMAs).
#define STEP_SYNC_PREFETCH() do {                                               \
    __syncthreads();                                                            \
    int cn_ = c + 1;                                                            \
    if (cn_ < NCHUNK) {                                                         \
        const u32x4* gsrc_ = ws + cn_ * 512 + wv * 128 + lane;                  \
        u32x4* ldst_ = &ring[cn_ & 1][wv * 128];                                \
        __builtin_amdgcn_global_load_lds(                                       \
            (const __attribute__((address_space(1))) void*)gsrc_,               \
            (__attribute__((address_space(3))) void*)ldst_, 16, 0, 0);          \
        __builtin_amdgcn_global_load_lds(                                       \
            (const __attribute__((address_space(1))) void*)(gsrc_ + 64),        \
            (__attribute__((address_space(3))) void*)(ldst_ + 64), 16, 0, 0);   \
    }                                                                           \
} while (0)

// bias-init one acc tile from LDS bias block (C/D order)
#define BINIT(dst, boff) do {                                                   \
    const f32x4* b4_ = (const f32x4*)(biasl + (boff) + hi * 16);                \
    const f32x4 v0_ = b4_[0], v1_ = b4_[1], v2_ = b4_[2], v3_ = b4_[3];         \
    _Pragma("unroll")                                                           \
    for (int j = 0; j < 4; ++j) {                                               \
        (dst)[j] = v0_[j]; (dst)[4 + j] = v1_[j];                               \
        (dst)[8 + j] = v2_[j]; (dst)[12 + j] = v3_[j];                          \
    }                                                                           \
} while (0)

// Zero-shuffle epilogue: C/D regs -> ReLU -> f16 -> next-layer B-frags in place.
#define EPI() do {                                                              \
    _Pragma("unroll")                                                           \
    for (int mt = 0; mt < 8; ++mt) {                                            \
        _Pragma("unroll")                                                       \
        for (int q = 0; q < 2; ++q) {                                           \
            u32x4 w;                                                            \
            w[0] = relu_pk(acc[mt][8*q+0], acc[mt][8*q+1]);                     \
            w[1] = relu_pk(acc[mt][8*q+2], acc[mt][8*q+3]);                     \
            w[2] = relu_pk(acc[mt][8*q+4], acc[mt][8*q+5]);                     \
            w[3] = relu_pk(acc[mt][8*q+6], acc[mt][8*q+7]);                     \
            xf[2*mt+q] = w;                                                     \
        }                                                                       \
    }                                                                           \
} while (0)

// L3 half-step with COMPILE-TIME xf base (rule #20: runtime half*8+i had
// demoted xf[] to scratch -> 785MB of spill traffic in Round 8).
#define L3_STEP(HBASE) do {                                                     \
    STEP_SYNC_PREFETCH();                                                       \
    const u32x4* bufq = &ring[c & 1][0];                                        \
    _Pragma("unroll")                                                           \
    for (int i = 0; i < 8; ++i) {                                               \
        const f16x8 a = __builtin_bit_cast(f16x8, bufq[i * 64 + lane]);         \
        c3 = __builtin_amdgcn_mfma_f32_32x32x16_f16(                            \
                a, __builtin_bit_cast(f16x8, xf[(HBASE) + i]), c3, 0, 0, 0);    \
    }                                                                           \
    ++c;                                                                        \
} while (0)

// ---------------- fused dual-MLP kernel ----------------
// 256 thr = 4 waves/block, 32 points/wave, 128 points/block, grid 2048.
// Shared double-buffered chunk pipeline over the 70-chunk weight stream;
// plain __syncthreads() (full drain) -- no inline-asm sync.
__launch_bounds__(256, 2)
__global__ void mlp_kernel(const float* __restrict__ gn, const float* __restrict__ gv,
                           const float* __restrict__ gro, const float* __restrict__ gr0,
                           const f16* __restrict__ wpk, const float* __restrict__ bpk,
                           float* __restrict__ out)
{
    __shared__ u32x4 ring[2][512];                 // 16KB double buffer
    __shared__ __align__(16) float biasl[1600];    // 6.4KB biases

    const int tid  = threadIdx.x;
    const int wv   = tid >> 6;
    const int lane = tid & 63;
    const int l32  = lane & 31;
    const int hi   = lane >> 5;
    const int p    = blockIdx.x * 128 + wv * 32 + l32;
    const u32x4* ws = (const u32x4*)wpk;           // 70-chunk contiguous stream

    // ---- biases -> LDS ----
    biasl[tid]        = bpk[tid];
    biasl[tid + 256]  = bpk[tid + 256];
    biasl[tid + 512]  = bpk[tid + 512];
    biasl[tid + 768]  = bpk[tid + 768];
    biasl[tid + 1024] = bpk[tid + 1024];
    biasl[tid + 1280] = bpk[tid + 1280];
    if (tid < 64) biasl[tid + 1536] = bpk[tid + 1536];

    // ---- prologue: stage chunk 0 ----
    {
        const u32x4* gsrc_ = ws + wv * 128 + lane;
        u32x4* ldst_ = &ring[0][wv * 128];
        __builtin_amdgcn_global_load_lds(
            (const __attribute__((address_space(1))) void*)gsrc_,
            (__attribute__((address_space(3))) void*)ldst_, 16, 0, 0);
        __builtin_amdgcn_global_load_lds(
            (const __attribute__((address_space(1))) void*)(gsrc_ + 64),
            (__attribute__((address_space(3))) void*)(ldst_ + 64), 16, 0, 0);
    }

    // ---- inputs ----
    u32x4 xd = {0,0,0,0}, xs = {0,0,0,0};
    bool vis = false;
    if (hi == 0) {               // hi lanes hold k=8..15 (zero-padded)
        float nx = gn[3*p], ny = gn[3*p+1], nz = gn[3*p+2];
        float vx = gv[3*p], vy = gv[3*p+1], vz = gv[3*p+2];
        float ro = gro[p], rr = gr0[p];
        float ni = 1.0f / fmaxf(sqrtf(nx*nx + ny*ny + nz*nz), 1e-12f);
        float vi = 1.0f / fmaxf(sqrtf(vx*vx + vy*vy + vz*vz), 1e-12f);
        nx *= ni; ny *= ni; nz *= ni; vx *= vi; vy *= vi; vz *= vi;
        vis = (nx*vx + ny*vy + nz*vz) > 0.0f;
        xd[0] = pkrtz(nx, ny); xd[1] = pkrtz(nz, 0.0f);
        xs[0] = xd[0];         xs[1] = pkrtz(nz, vx);
        xs[2] = pkrtz(vy, vz); xs[3] = pkrtz(ro, rr);
    }

    f32x16 acc[8];    // 128 regs (AGPR-eligible)
    u32x4  xf[16];    // 64 VGPRs (ALL indices compile-time constant)
    int c = 0;        // global chunk index (0..69)

    #pragma unroll 1
    for (int net = 0; net < 2; ++net) {
        const int bb = net * 800;
        const f16x8 xh0 = __builtin_bit_cast(f16x8, net ? xs : xd);

        // ---------- L0 (1 chunk) ----------
        STEP_SYNC_PREFETCH();
        {
            const u32x4* bufq = &ring[c & 1][0];
            #pragma unroll
            for (int mt = 0; mt < 8; ++mt) {
                f32x16 ci;
                BINIT(ci, bb + mt * 32);
                const f16x8 a = __builtin_bit_cast(f16x8, bufq[mt * 64 + lane]);
                acc[mt] = __builtin_amdgcn_mfma_f32_32x32x16_f16(a, xh0, ci, 0, 0, 0);
            }
        }
        ++c;
        EPI();

        // ---------- L1, L2 (16 chunks each) ----------
        #pragma unroll 1
        for (int layer = 0; layer < 2; ++layer) {
            #pragma unroll
            for (int mt = 0; mt < 8; ++mt) BINIT(acc[mt], bb + 256 + layer * 256 + mt * 32);
            #pragma unroll
            for (int kt = 0; kt < 16; ++kt) {
                STEP_SYNC_PREFETCH();
                const u32x4* bufq = &ring[c & 1][0];
                const f16x8 xh = __builtin_bit_cast(f16x8, xf[kt]);
                #pragma unroll
                for (int mt = 0; mt < 8; ++mt) {
                    const f16x8 a = __builtin_bit_cast(f16x8, bufq[mt * 64 + lane]);
                    acc[mt] = __builtin_amdgcn_mfma_f32_32x32x16_f16(a, xh, acc[mt], 0, 0, 0);
                }
                ++c;
            }
            EPI();
        }

        // ---------- L3: 256 -> 3 (2 chunks, STATIC xf indexing) ----------
        {
            f32x16 c3;
            BINIT(c3, bb + 768);
            L3_STEP(0);
            L3_STEP(8);
            if (hi == 0) {
                float* op = out + net * (NPTS * 3) + p * 3;
                op[0] = vis ? c3[0] : 0.0f;
                op[1] = vis ? c3[1] : 0.0f;
                op[2] = vis ? c3[2] : 0.0f;
            }
        }
    }
}

extern "C" void kernel_launch(void* const* d_in, const int* in_sizes, int n_in,
                              void* d_out, int out_size, void* d_ws, size_t ws_size,
                              hipStream_t stream)
{
    f16*   wpk = (f16*)d_ws;
    float* bpk = (float*)((char*)d_ws + BIAS_BYTE);

    prep_kernel<<<147, 256, 0, stream>>>(
        (const float*)d_in[4],  (const float*)d_in[5],
        (const float*)d_in[6],  (const float*)d_in[7],
        (const float*)d_in[8],  (const float*)d_in[9],
        (const float*)d_in[10], (const float*)d_in[11],
        (const float*)d_in[12], (const float*)d_in[13],
        (const float*)d_in[14], (const float*)d_in[15],
        (const float*)d_in[16], (const float*)d_in[17],
        (const float*)d_in[18], (const float*)d_in[19],
        wpk, bpk);

    mlp_kernel<<<2048, 256, 0, stream>>>(
        (const float*)d_in[0], (const float*)d_in[1],
        (const float*)d_in[2], (const float*)d_in[3],
        wpk, bpk, (float*)d_out);
}